// Round 5
// baseline (180.571 us; speedup 1.0000x reference)
//
#include <hip/hip_runtime.h>
#include <math.h>

// DCT2net, R10: sliding-window vDCT recurrence + scaled domain + k3 symmetry.
//
// R9 post-mortem: dur flat, VALUBusy 76->85% (occupancy 18->29%): now truly
// VALU-issue bound at ~710 instr-equiv/step. R10 cuts instructions structurally:
//  - vDCT via sliding-DCT recurrence (Kober): t_i(m) = 2cos(i*pi/13)*t_i(m-1)
//    - t_i(m-2) + k_i*[R(m-2)-R(m-1)] + (-1)^i*k_i*[R(m+12)-R(m+11)],
//    k_i = s*Ci*cos(i*pi/26). 2 FMA/coeff vs 7 FMA + setup. Bootstrap: 2 direct
//    matvecs per segment (k=12,13). Rv ring replaced by 13-deep difference ring.
//  - scaled domain: c1col *= inv3s once -> t arrives pre-scaled for shrink
//    (saves *i2sq per coeff); k3 multiplies final out by 3*sigma.
//  - T0/T1 ping-pong via explicit 2-step pairs (no copies); runtime retire flag
//    so steady loop is ONE pair body (~16KB I$, R8 lesson).
//  - k3: row symmetry c1[12-dy][j] = (-1)^j c1[dy][j] -> U-build 169 -> ~98 FMA;
//    As SGPR pool (k3 was materializing 169 literal movs).
//
// ws: Hg = 2*488*512*16 f32 (31.98 MB), Wg = 2*512*512 f32 (2 MB).

#define P13    13
#define IMGW   512
#define OUTW   488
#define SEGH   31      // 15*31 + 23 = 488
#define NSEG   16
#define HCOLS  512
#define HPITCH 16

struct C1mat { float v[P13 * P13]; };

// ---- compile-time DCT tables ----
constexpr double kPI = 3.14159265358979323846264338327950288;

constexpr double ccos_pm_pi(double th) {   // Taylor, |th| <= pi
    double term = 1.0, s = 1.0;
    const double th2 = th * th;
    for (int n = 1; n <= 25; ++n) {
        term *= -th2 / (double)((2 * n - 1) * (2 * n));
        s += term;
    }
    return s;
}
constexpr double csqrt(double v) {
    double x = (v > 1.0) ? v : 1.0;
    for (int i = 0; i < 64; ++i) x = 0.5 * (x + v / x);
    return x;
}
constexpr C1mat make_c1() {
    C1mat m{};
    const double s213 = csqrt(2.0 / 13.0);
    const double is2  = 1.0 / csqrt(2.0);
    for (int x = 0; x < P13; ++x)
        for (int k = 0; k < P13; ++k) {
            int mm = ((2 * x + 1) * k) % 52;
            double th = (mm <= 26) ? (mm * kPI / 26.0) : ((mm - 52) * kPI / 26.0);
            double Ci = (k == 0) ? is2 : 1.0;
            m.v[x * P13 + k] = (float)(s213 * Ci * ccos_pm_pi(th));
        }
    return m;
}
__device__ constexpr C1mat c1c = make_c1();

// c1[r][c] = sgn*A[idx]; A[q] = s213*cos(q*pi/26) (q=0..12), A[13] = s213/sqrt(2).
// b[q] = 2*cos((q+1)*pi/13), q=0..5 (recurrence constants; i=0 uses inline 2.0,
// i=7..12 use -b[12-i-? ] via sign modifier).
struct CTab { int idx[P13][P13]; bool neg[P13][P13]; float a[14]; float b[6]; };
constexpr CTab make_ctab() {
    CTab t{};
    const double s213 = csqrt(2.0 / 13.0);
    for (int q = 0; q <= 12; ++q) t.a[q] = (float)(s213 * ccos_pm_pi(q * kPI / 26.0));
    t.a[13] = (float)(s213 / csqrt(2.0));
    for (int q = 0; q < 6; ++q) t.b[q] = (float)(2.0 * ccos_pm_pi((q + 1) * kPI / 13.0));
    for (int r = 0; r < P13; ++r)
        for (int c = 0; c < P13; ++c) {
            if (c == 0) { t.idx[r][c] = 13; t.neg[r][c] = false; continue; }
            int m = ((2 * r + 1) * c) % 52;
            int q; bool n;
            if (m <= 13)      { q = m;      n = false; }
            else if (m <= 26) { q = 26 - m; n = true;  }
            else if (m <= 39) { q = m - 26; n = true;  }
            else              { q = 52 - m; n = false; }
            t.idx[r][c] = q; t.neg[r][c] = n;
        }
    return t;
}
constexpr CTab ctab = make_ctab();

// compile-time-folded signed SGPR constant (r,c constant after unroll)
#define KC(r, c) (ctab.neg[(r)][(c)] ? -As[ctab.idx[(r)][(c)]] : As[ctab.idx[(r)][(c)]])

struct FalseT { static constexpr bool value = false; };
struct TrueT  { static constexpr bool value = true; };

// rotate-reduce add within each 16-lane DPP row: N in {1,2,4,8}
#define ROR16_ADD(v, N)                                                        \
    v += __int_as_float(__builtin_amdgcn_mov_dpp(__float_as_int(v),            \
                                                 0x120 + (N), 0xF, 0xF, true))

// weighted vertical inverse fold (scaled domain: tn, H both carry inv3s)
__device__ __forceinline__ void fold_vert(const float (&tn)[P13], const float (&As)[14],
                                          float w1, float (&H)[P13])
{
#pragma unroll
    for (int dx = 0; dx < 6; ++dx) {
        float E = KC(dx, 0) * tn[0];
#pragma unroll
        for (int i = 2; i < P13; i += 2) E = fmaf(KC(dx, i), tn[i], E);
        float O = KC(dx, 1) * tn[1];
#pragma unroll
        for (int i = 3; i < P13; i += 2) O = fmaf(KC(dx, i), tn[i], O);
        H[dx]      = fmaf(w1, E + O, H[dx]);
        H[12 - dx] = fmaf(w1, E - O, H[12 - dx]);
    }
    float z6 = KC(6, 0) * tn[0];
#pragma unroll
    for (int i = 2; i < P13; i += 2) z6 = fmaf(KC(6, i), tn[i], z6);
    H[6] = fmaf(w1, z6, H[6]);
}

__global__ __launch_bounds__(256) void dct2net_k2(
    const float* __restrict__ xg, const float* __restrict__ sigmag,
    float* __restrict__ Hg, float* __restrict__ Wg)
{
    __shared__ float c1lds[169];
    const int tid = threadIdx.x;
    if (tid < 169) c1lds[tid] = c1c.v[tid];
    __syncthreads();                       // once, for the c1 table only

    const int lane = tid & 63;
    const int wv   = tid >> 6;
    const int g    = lane >> 4;            // col group 0..3
    const int jj   = lane & 15;            // kj (0..12 used)
    const int img  = blockIdx.z;
    const int hs   = blockIdx.y * SEGH;
    const int segrows = (OUTW - hs < SEGH) ? (OUTW - hs) : SEGH;
    const int cbw  = blockIdx.x * 16 + wv * 4;
    const int col  = cbw + g;

    const float inv3s = 1.0f / (3.0f * sigmag[0]);
    const float* xin  = xg + (size_t)img * IMGW * IMGW;

    // SGPR constant pools (14 magnitudes + 6 recurrence cosines)
    float As[14], Bs[6];
#pragma unroll
    for (int q = 0; q < 14; ++q) As[q] = ctab.a[q];
#pragma unroll
    for (int q = 0; q < 6; ++q) Bs[q] = ctab.b[q];
#pragma unroll
    for (int q = 0; q < 14; ++q) asm("" : "+s"(As[q]));
#pragma unroll
    for (int q = 0; q < 6; ++q) asm("" : "+s"(Bs[q]));

    // per-lane c1 column for the hDCT, PRE-SCALED by inv3s (scaled domain)
    float c1col[P13];
#pragma unroll
    for (int y = 0; y < P13; ++y)
        c1col[y] = (jj < 13) ? c1lds[y * P13 + jj] * inv3s : 0.0f;

    float T0[P13], T1[P13], dr[P13], Hr[P13], wr[12], Rv[P13];
#pragma unroll
    for (int k = 0; k < P13; ++k) { T0[k]=0; T1[k]=0; dr[k]=0; Hr[k]=0; Rv[k]=0; }
#pragma unroll
    for (int k = 0; k < 12; ++k) wr[k] = 0.0f;
    float vs = 0.0f, Rprev = 0.0f;

    int xcol = cbw + (lane & 15); xcol = (xcol < IMGW - 1) ? xcol : (IMGW - 1);
    const float* xp    = xin + (size_t)hs * IMGW;
    const float* xlast = xin + (size_t)(IMGW - 1) * IMGW;
    float xv = xp[xcol];                   // all 64 lanes; dup cols coalesce
    xp += IMGW;

    float* Hp = Hg + ((size_t)img * OUTW + hs) * HCOLS * HPITCH;
    float* Wp = Wg + ((size_t)img * IMGW + hs) * IMGW;
    const int voH = col * HPITCH + jj;
    const int voW = col;

    // gather + hDCT + prefetch -> new (scaled) hDCT value for this row
    auto front = [&]() -> float {
        float xw[P13];
#pragma unroll
        for (int y = 0; y < P13; ++y)
            xw[y] = __int_as_float(
                __builtin_amdgcn_ds_bpermute(4 * (g + y), __float_as_int(xv)));
        { const float* xq = (xp < xlast) ? xp : xlast; xv = xq[xcol]; xp += IMGW; }
        float a0 = c1col[0] * xw[0], a1 = c1col[1] * xw[1];
#pragma unroll
        for (int y = 2; y < P13; y += 2) a0 = fmaf(c1col[y], xw[y], a0);
#pragma unroll
        for (int y = 3; y < P13; y += 2) a1 = fmaf(c1col[y], xw[y], a1);
        return a0 + a1;
    };
    auto pushRv = [&](float Rn) {
#pragma unroll
        for (int q = 0; q < P13 - 1; ++q) Rv[q] = Rv[q + 1];
        Rv[P13 - 1] = Rn;
    };
    auto pushd = [&](float Rn) {           // difference ring (boundary terms)
        float dn = Rn - Rprev; Rprev = Rn;
#pragma unroll
        for (int q = 0; q < P13 - 1; ++q) dr[q] = dr[q + 1];
        dr[P13 - 1] = dn;
    };
    // direct vDCT matvec from Rv (bootstrap only)
    auto matvec = [&](float (&T)[P13]) {
        float Se[6], So[6];
#pragma unroll
        for (int k = 0; k < 6; ++k) { Se[k] = Rv[k] + Rv[12 - k]; So[k] = Rv[k] - Rv[12 - k]; }
#pragma unroll
        for (int i = 0; i < P13; ++i) {
            float t;
            if ((i & 1) == 0) {
                t = KC(6, i) * Rv[6];
#pragma unroll
                for (int k = 0; k < 6; ++k) t = fmaf(KC(k, i), Se[k], t);
            } else {
                t = KC(0, i) * So[0];
#pragma unroll
                for (int k = 1; k < 6; ++k) t = fmaf(KC(k, i), So[k], t);
            }
            T[i] = t;
        }
    };
    // shrink + butterfly + fold + (runtime) retire. T is pre-scaled (u = t).
    auto sf = [&](const float (&T)[P13], bool rt) {
        float tn[P13]; float pnzr = 0.0f;
#pragma unroll
        for (int i = 0; i < P13; ++i) {
            float p2 = fminf(T[i] * T[i], 1.69f);   // == med3-clamp squared
            float p4 = p2 * p2, p8 = p4 * p4, p16 = p8 * p8, p32 = p16 * p16, p64 = p32 * p32;
            float r  = __builtin_amdgcn_rcpf(p64 + 1.0f);
            pnzr += r;
            tn[i] = fmaf(-T[i], r, T[i]);           // t*nz, nz = 1-r
        }
        float pnz = 13.0f - pnzr;                   // idle lanes: exactly 0
        ROR16_ADD(pnz, 1); ROR16_ADD(pnz, 2); ROR16_ADD(pnz, 4); ROR16_ADD(pnz, 8);
        const float w = __builtin_amdgcn_rcpf(1.0f + pnz);
        vs += w;
        fold_vert(tn, As, w, Hr);
        if (rt) {                                   // uniform branch (SALU)
            Hp[voH] = Hr[0];
            Hp += HCOLS * HPITCH;
            if (jj == 0) Wp[voW] = vs;
            Wp += IMGW;
            vs -= wr[0];
        }
#pragma unroll
        for (int q = 0; q < 11; ++q) wr[q] = wr[q + 1];
        wr[11] = w;
#pragma unroll
        for (int q = 0; q < P13 - 1; ++q) Hr[q] = Hr[q + 1];
        Hr[P13 - 1] = 0.0f;
    };
    // recurrence step: t(m) = 2cos(i*pi/13)*t(m-1) - t(m-2) + boundary
    auto recur = [&](auto INTOT0, bool rt) {
        float Rn = front();
        float dn = Rn - Rprev; Rprev = Rn;
        float dl = dr[0];                           // R(m-1)-R(m-2), 13 steps old
#pragma unroll
        for (int q = 0; q < P13 - 1; ++q) dr[q] = dr[q + 1];
        dr[P13 - 1] = dn;
        float Pe = dn - dl, Po = dn + dl;
#pragma unroll
        for (int i = 0; i < P13; ++i) {
            float tp2 = decltype(INTOT0)::value ? T0[i] : T1[i];  // t(m-2)
            float tp1 = decltype(INTOT0)::value ? T1[i] : T0[i];  // t(m-1)
            float c2 = (i == 0) ? 2.0f : ((i <= 6) ? Bs[i - 1] : -Bs[12 - i]);
            float t = fmaf(c2, tp1, -tp2);
            float kc = (i == 0) ? As[13] : As[i];
            t = (i & 1) ? fmaf(-kc, Po, t) : fmaf(kc, Pe, t);
            if constexpr (decltype(INTOT0)::value) T0[i] = t; else T1[i] = t;
        }
        if constexpr (decltype(INTOT0)::value) sf(T0, rt); else sf(T1, rt);
    };

    // ---- ramp1: fill Rv + difference ring (k=0..11) ----
    { float Rn = front(); Rprev = Rn; pushRv(Rn); }       // k=0 (no diff yet)
#pragma unroll 1
    for (int k = 1; k < 12; ++k) { float Rn = front(); pushd(Rn); pushRv(Rn); }
    // ---- bootstrap: direct matvecs at k=12 (t(0)->T0), k=13 (t(1)->T1) ----
    { float Rn = front(); pushd(Rn); pushRv(Rn); matvec(T0); sf(T0, false); }
    { float Rn = front(); pushd(Rn); pushRv(Rn); matvec(T1); sf(T1, false); }
    // ---- steady: recurrence pairs; retire from steady-step 10 on ----
    {
        int ks = 0; const int S = 10 + segrows;           // k = 14 .. 23+segrows
#pragma unroll 1
        while (ks + 2 <= S) {
            recur(TrueT{},  ks     >= 10);
            recur(FalseT{}, ks + 1 >= 10);
            ks += 2;
        }
        if (ks < S) recur(TrueT{}, ks >= 10);
    }
}

__global__ __launch_bounds__(256) void dct2net_k3(
    const float* __restrict__ Hg, const float* __restrict__ Wg,
    const float* __restrict__ sigmag, float* __restrict__ outg)
{
    __shared__ float U[4][76][14];   // stride 14: 2-way bank alias only (free)
    __shared__ float vw[4][80];
    const int tid  = threadIdx.x;
    const int lane = tid & 63;
    const int wv   = tid >> 6;
    const int img  = blockIdx.z;
    const int a0   = blockIdx.y * 4;
    const int a    = a0 + wv;               // out row (<= 487)
    const int cb   = blockIdx.x * 64;       // out col base

    const float t3s = 3.0f * sigmag[0];     // undo k2's scaled domain

    float As[14];
#pragma unroll
    for (int q = 0; q < 14; ++q) As[q] = ctab.a[q];
#pragma unroll
    for (int q = 0; q < 14; ++q) asm("" : "+s"(As[q]));

    // ---- issue all loads up front (main + halo) ----
    int c = cb + lane; c = (c < 499) ? c : 499;
    const float* hp = &Hg[(((size_t)img * OUTW + a) * HCOLS + c) * HPITCH];
    float4 m0 = *(const float4*)hp;
    float4 m1 = *(const float4*)(hp + 4);
    float4 m2 = *(const float4*)(hp + 8);
    float  m3 = hp[12];
    float  wm = Wg[((size_t)img * IMGW + a) * IMGW + c];

    const bool halo = (tid < 48);           // wave 0: 4 rows x 12 halo cols
    const int  hr = tid / 12;
    const int  hm = tid - hr * 12;
    float4 s0 = {0,0,0,0}, s1 = {0,0,0,0}, s2 = {0,0,0,0};
    float  s3 = 0.0f, ws = 0.0f;
    if (halo) {
        const int ah = a0 + hr;
        int c2 = cb + 64 + hm; c2 = (c2 < 499) ? c2 : 499;
        const float* hq = &Hg[(((size_t)img * OUTW + ah) * HCOLS + c2) * HPITCH];
        s0 = *(const float4*)hq;
        s1 = *(const float4*)(hq + 4);
        s2 = *(const float4*)(hq + 8);
        s3 = hq[12];
        ws = Wg[((size_t)img * IMGW + ah) * IMGW + c2];
    }

    // U[dy] build with row symmetry: c1[12-dy][j] = (-1)^j c1[dy][j]
    auto buildU = [&](const float (&hv)[P13], int uw, int uli) {
#pragma unroll
        for (int dy = 0; dy < 6; ++dy) {
            float e = KC(dy, 0) * hv[0];
#pragma unroll
            for (int j = 2; j < P13; j += 2) e = fmaf(KC(dy, j), hv[j], e);
            float o = KC(dy, 1) * hv[1];
#pragma unroll
            for (int j = 3; j < P13; j += 2) o = fmaf(KC(dy, j), hv[j], o);
            U[uw][uli][dy]      = e + o;
            U[uw][uli][12 - dy] = e - o;
        }
        // dy=6: c1[6][j] = 0 for odd j; (-1)^(j/2) * s for even j (C0 = 1/sqrt2)
        float gsum = ((hv[4] - hv[2]) + (hv[8] - hv[6])) + (hv[12] - hv[10]);
        U[uw][uli][6] = fmaf(As[0], gsum, As[13] * hv[0]);
    };

    {
        float hv[P13] = {m0.x,m0.y,m0.z,m0.w, m1.x,m1.y,m1.z,m1.w,
                         m2.x,m2.y,m2.z,m2.w, m3};
        buildU(hv, wv, lane);
        vw[wv][lane] = wm;
    }
    if (halo) {
        float hv[P13] = {s0.x,s0.y,s0.z,s0.w, s1.x,s1.y,s1.z,s1.w,
                         s2.x,s2.y,s2.z,s2.w, s3};
        buildU(hv, hr, 64 + hm);
        vw[hr][64 + hm] = ws;
    }
    __syncthreads();

    float num = 0.0f;
#pragma unroll
    for (int dy = 0; dy < P13; ++dy) num += U[wv][lane + 12 - dy][dy];
    float den = 0.0f;
#pragma unroll
    for (int d = 0; d < P13; ++d) den += vw[wv][lane + d];
    const int ow = cb + lane;
    if (ow < OUTW)
        outg[((size_t)img * OUTW + a) * OUTW + ow] =
            num * t3s * __builtin_amdgcn_rcpf(den);
}

extern "C" void kernel_launch(void* const* d_in, const int* in_sizes, int n_in,
                              void* d_out, int out_size, void* d_ws, size_t ws_size,
                              hipStream_t stream)
{
    const float* x     = (const float*)d_in[0];
    const float* sigma = (const float*)d_in[1];
    float* out = (float*)d_out;

    // ws: Hg (2*488*512*16 f32 = 31.98 MB) then Wg (2*512*512 f32 = 2 MB)
    float* Hg = (float*)d_ws;
    float* Wg = Hg + (size_t)2 * OUTW * HCOLS * HPITCH;

    dct2net_k2<<<dim3(32, NSEG, 2), 256, 0, stream>>>(x, sigma, Hg, Wg);
    dct2net_k3<<<dim3(8, 122, 2), 256, 0, stream>>>(Hg, Wg, sigma, out);
}

// Round 6
// 176.659 us; speedup vs baseline: 1.0221x; 1.0221x over previous
//
#include <hip/hip_runtime.h>
#include <math.h>

// DCT2net, R11: LDS-staged window gather (5 LDS ops vs 13 bpermute) +
// 2-ahead prefetch + jj-plane Hg layout (coalesced k3 loads).
//
// R10 post-mortem: dur pinned at 129us for 3 rounds while VALUBusy fell
// 85->72% => k2 is bound by the per-step 13x ds_bpermute + lgkm chain with
// only 4 waves/SIMD, not by VALU issue. k3 tail ~50us vs ~2us throughput
// cost => its 64B-stride Hg gather (1 line per lane per load) is the pin.
//
// R11 changes:
//  - k2 gather: stage 16-wide x window in LDS (1 ds_write_b32, 4 padded
//    replicas, <=2-way conflict) + 4 aligned ds_read_b128 (group-broadcast,
//    conflict-free at 80B stride). Per-lane precomputed c1x[16] (zero-masked
//    window coeffs) -> hDCT = 16 FMA, no bpermute, no exec masks.
//  - 2-row-ahead pipeline: load row k+2 / stage row k+1 / consume row k.
//  - Hg transposed to [img][a][jj][col]: k2 store scatters (16x16B, cheap),
//    k3's 13 loads become fully coalesced (256B/instr).
//  - k3: U stride 14->15 (diag-read 4-way -> 2-way bank alias, free).
//  - keeps R10: sliding-DCT recurrence, scaled domain, SGPR const pools,
//    DPP ROR16 butterfly, runtime retire flag, pair-unrolled T0/T1.
//
// ws: Hg = 2*488*16*512 f32 (31.98 MB), Wg = 2*512*512 f32 (2 MB).

#define P13    13
#define IMGW   512
#define OUTW   488
#define SEGH   31      // 15*31 + 23 = 488
#define NSEG   16
#define HCOLS  512
#define HPITCH 16

struct C1mat { float v[P13 * P13]; };

// ---- compile-time DCT tables ----
constexpr double kPI = 3.14159265358979323846264338327950288;

constexpr double ccos_pm_pi(double th) {   // Taylor, |th| <= pi
    double term = 1.0, s = 1.0;
    const double th2 = th * th;
    for (int n = 1; n <= 25; ++n) {
        term *= -th2 / (double)((2 * n - 1) * (2 * n));
        s += term;
    }
    return s;
}
constexpr double csqrt(double v) {
    double x = (v > 1.0) ? v : 1.0;
    for (int i = 0; i < 64; ++i) x = 0.5 * (x + v / x);
    return x;
}
constexpr C1mat make_c1() {
    C1mat m{};
    const double s213 = csqrt(2.0 / 13.0);
    const double is2  = 1.0 / csqrt(2.0);
    for (int x = 0; x < P13; ++x)
        for (int k = 0; k < P13; ++k) {
            int mm = ((2 * x + 1) * k) % 52;
            double th = (mm <= 26) ? (mm * kPI / 26.0) : ((mm - 52) * kPI / 26.0);
            double Ci = (k == 0) ? is2 : 1.0;
            m.v[x * P13 + k] = (float)(s213 * Ci * ccos_pm_pi(th));
        }
    return m;
}
__device__ constexpr C1mat c1c = make_c1();

// c1[r][c] = sgn*A[idx]; A[q] = s213*cos(q*pi/26) (q=0..12), A[13] = s213/sqrt2.
// b[q] = 2*cos((q+1)*pi/13), q=0..5 (sliding-DCT recurrence constants).
struct CTab { int idx[P13][P13]; bool neg[P13][P13]; float a[14]; float b[6]; };
constexpr CTab make_ctab() {
    CTab t{};
    const double s213 = csqrt(2.0 / 13.0);
    for (int q = 0; q <= 12; ++q) t.a[q] = (float)(s213 * ccos_pm_pi(q * kPI / 26.0));
    t.a[13] = (float)(s213 / csqrt(2.0));
    for (int q = 0; q < 6; ++q) t.b[q] = (float)(2.0 * ccos_pm_pi((q + 1) * kPI / 13.0));
    for (int r = 0; r < P13; ++r)
        for (int c = 0; c < P13; ++c) {
            if (c == 0) { t.idx[r][c] = 13; t.neg[r][c] = false; continue; }
            int m = ((2 * r + 1) * c) % 52;
            int q; bool n;
            if (m <= 13)      { q = m;      n = false; }
            else if (m <= 26) { q = 26 - m; n = true;  }
            else if (m <= 39) { q = m - 26; n = true;  }
            else              { q = 52 - m; n = false; }
            t.idx[r][c] = q; t.neg[r][c] = n;
        }
    return t;
}
constexpr CTab ctab = make_ctab();

#define KC(r, c) (ctab.neg[(r)][(c)] ? -As[ctab.idx[(r)][(c)]] : As[ctab.idx[(r)][(c)]])

struct FalseT { static constexpr bool value = false; };
struct TrueT  { static constexpr bool value = true; };

// rotate-reduce add within each 16-lane DPP row: N in {1,2,4,8}
#define ROR16_ADD(v, N)                                                        \
    v += __int_as_float(__builtin_amdgcn_mov_dpp(__float_as_int(v),            \
                                                 0x120 + (N), 0xF, 0xF, true))

// weighted vertical inverse fold (scaled domain)
__device__ __forceinline__ void fold_vert(const float (&tn)[P13], const float (&As)[14],
                                          float w1, float (&H)[P13])
{
#pragma unroll
    for (int dx = 0; dx < 6; ++dx) {
        float E = KC(dx, 0) * tn[0];
#pragma unroll
        for (int i = 2; i < P13; i += 2) E = fmaf(KC(dx, i), tn[i], E);
        float O = KC(dx, 1) * tn[1];
#pragma unroll
        for (int i = 3; i < P13; i += 2) O = fmaf(KC(dx, i), tn[i], O);
        H[dx]      = fmaf(w1, E + O, H[dx]);
        H[12 - dx] = fmaf(w1, E - O, H[12 - dx]);
    }
    float z6 = KC(6, 0) * tn[0];
#pragma unroll
    for (int i = 2; i < P13; i += 2) z6 = fmaf(KC(6, i), tn[i], z6);
    H[6] = fmaf(w1, z6, H[6]);
}

__global__ __launch_bounds__(256) void dct2net_k2(
    const float* __restrict__ xg, const float* __restrict__ sigmag,
    float* __restrict__ Hg, float* __restrict__ Wg)
{
    __shared__ float c1lds[169];
    __shared__ float xlds[4][4][20];       // [wave][group][16 used + 4 pad]
    const int tid = threadIdx.x;
    if (tid < 169) c1lds[tid] = c1c.v[tid];
    __syncthreads();                       // once, for the c1 table only

    const int lane = tid & 63;
    const int wv   = tid >> 6;
    const int g    = lane >> 4;            // col group 0..3
    const int jj   = lane & 15;            // kj (0..12 used)
    const int img  = blockIdx.z;
    const int hs   = blockIdx.y * SEGH;
    const int segrows = (OUTW - hs < SEGH) ? (OUTW - hs) : SEGH;
    const int cbw  = blockIdx.x * 16 + wv * 4;
    const int col  = cbw + g;

    const float inv3s = 1.0f / (3.0f * sigmag[0]);
    const float* xin  = xg + (size_t)img * IMGW * IMGW;

    // SGPR constant pools
    float As[14], Bs[6];
#pragma unroll
    for (int q = 0; q < 14; ++q) As[q] = ctab.a[q];
#pragma unroll
    for (int q = 0; q < 6; ++q) Bs[q] = ctab.b[q];
#pragma unroll
    for (int q = 0; q < 14; ++q) asm("" : "+s"(As[q]));
#pragma unroll
    for (int q = 0; q < 6; ++q) asm("" : "+s"(Bs[q]));

    // per-lane window coefficients over staged positions p=0..15:
    // c1x[p] = c1[p-g][jj] * inv3s inside the window, 0 outside / idle lanes
    float c1x[16];
#pragma unroll
    for (int p = 0; p < 16; ++p) {
        int y = p - g;
        int yc = (y < 0) ? 0 : ((y > 12) ? 12 : y);
        int jc = (jj < 13) ? jj : 0;
        float v = c1lds[yc * 13 + jc];
        c1x[p] = (y >= 0 && y < 13 && jj < 13) ? v * inv3s : 0.0f;
    }

    float T0[P13], T1[P13], dr[P13], Hr[P13], wr[12], Rv[P13];
#pragma unroll
    for (int k = 0; k < P13; ++k) { T0[k]=0; T1[k]=0; dr[k]=0; Hr[k]=0; Rv[k]=0; }
#pragma unroll
    for (int k = 0; k < 12; ++k) wr[k] = 0.0f;
    float vs = 0.0f, Rprev = 0.0f;

    int xcol = cbw + (lane & 15); xcol = (xcol < IMGW - 1) ? xcol : (IMGW - 1);
    const float* xlast = xin + (size_t)(IMGW - 1) * IMGW;

    // ---- pre-roll: buf <- row hs; xvA <- row hs+1; xp -> row hs+2 ----
    float xvA, xvB;
    {
        const float* r0 = xin + (size_t)hs * IMGW;
        float t0 = r0[xcol];
        xlds[wv][g][jj] = t0;
        const float* r1 = xin + (size_t)(hs + 1) * IMGW;
        xvA = r1[xcol];
    }
    const float* xp = xin + (size_t)(hs + 2) * IMGW;

    float* Hp = Hg + ((size_t)img * OUTW + hs) * HPITCH * HCOLS;
    float* Wp = Wg + ((size_t)img * IMGW + hs) * IMGW;
    const int voH = jj * HCOLS + col;      // jj-plane layout
    const int voW = col;

    // gather staged row k (4x ds_read_b128 broadcast), prefetch row k+2 into
    // xvL, stage row k+1 (xvW). Returns the scaled hDCT value for row k.
    auto front = [&](float& xvW, float& xvL) -> float {
        float4 q0 = *(const float4*)&xlds[wv][g][0];
        float4 q1 = *(const float4*)&xlds[wv][g][4];
        float4 q2 = *(const float4*)&xlds[wv][g][8];
        float4 q3 = *(const float4*)&xlds[wv][g][12];
        { const float* xq = (xp < xlast) ? xp : xlast; xvL = xq[xcol]; xp += IMGW; }
        xlds[wv][g][jj] = xvW;             // after reads in program order
        float xq_[16] = {q0.x,q0.y,q0.z,q0.w, q1.x,q1.y,q1.z,q1.w,
                         q2.x,q2.y,q2.z,q2.w, q3.x,q3.y,q3.z,q3.w};
        float a0 = c1x[0] * xq_[0], a1 = c1x[1] * xq_[1];
#pragma unroll
        for (int p = 2; p < 16; p += 2) a0 = fmaf(c1x[p], xq_[p], a0);
#pragma unroll
        for (int p = 3; p < 16; p += 2) a1 = fmaf(c1x[p], xq_[p], a1);
        return a0 + a1;
    };
    auto pushRv = [&](float Rn) {
#pragma unroll
        for (int q = 0; q < P13 - 1; ++q) Rv[q] = Rv[q + 1];
        Rv[P13 - 1] = Rn;
    };
    auto pushd = [&](float Rn) {
        float dn = Rn - Rprev; Rprev = Rn;
#pragma unroll
        for (int q = 0; q < P13 - 1; ++q) dr[q] = dr[q + 1];
        dr[P13 - 1] = dn;
    };
    auto matvec = [&](float (&T)[P13]) {   // bootstrap only
        float Se[6], So[6];
#pragma unroll
        for (int k = 0; k < 6; ++k) { Se[k] = Rv[k] + Rv[12 - k]; So[k] = Rv[k] - Rv[12 - k]; }
#pragma unroll
        for (int i = 0; i < P13; ++i) {
            float t;
            if ((i & 1) == 0) {
                t = KC(6, i) * Rv[6];
#pragma unroll
                for (int k = 0; k < 6; ++k) t = fmaf(KC(k, i), Se[k], t);
            } else {
                t = KC(0, i) * So[0];
#pragma unroll
                for (int k = 1; k < 6; ++k) t = fmaf(KC(k, i), So[k], t);
            }
            T[i] = t;
        }
    };
    // shrink + butterfly + fold + (runtime) retire. T pre-scaled (u = t).
    auto sf = [&](const float (&T)[P13], bool rt) {
        float tn[P13]; float pnzr = 0.0f;
#pragma unroll
        for (int i = 0; i < P13; ++i) {
            float p2 = fminf(T[i] * T[i], 1.69f);
            float p4 = p2 * p2, p8 = p4 * p4, p16 = p8 * p8, p32 = p16 * p16, p64 = p32 * p32;
            float r  = __builtin_amdgcn_rcpf(p64 + 1.0f);
            pnzr += r;
            tn[i] = fmaf(-T[i], r, T[i]);
        }
        float pnz = 13.0f - pnzr;          // idle lanes: exactly 0
        ROR16_ADD(pnz, 1); ROR16_ADD(pnz, 2); ROR16_ADD(pnz, 4); ROR16_ADD(pnz, 8);
        const float w = __builtin_amdgcn_rcpf(1.0f + pnz);
        vs += w;
        fold_vert(tn, As, w, Hr);
        if (rt) {                           // uniform branch
            Hp[voH] = Hr[0];
            Hp += HPITCH * HCOLS;
            if (jj == 0) Wp[voW] = vs;
            Wp += IMGW;
            vs -= wr[0];
        }
#pragma unroll
        for (int q = 0; q < 11; ++q) wr[q] = wr[q + 1];
        wr[11] = w;
#pragma unroll
        for (int q = 0; q < P13 - 1; ++q) Hr[q] = Hr[q + 1];
        Hr[P13 - 1] = 0.0f;
    };
    auto recur = [&](auto INTOT0, float& xvW, float& xvL, bool rt) {
        float Rn = front(xvW, xvL);
        float dn = Rn - Rprev; Rprev = Rn;
        float dl = dr[0];
#pragma unroll
        for (int q = 0; q < P13 - 1; ++q) dr[q] = dr[q + 1];
        dr[P13 - 1] = dn;
        float Pe = dn - dl, Po = dn + dl;
#pragma unroll
        for (int i = 0; i < P13; ++i) {
            float tp2 = decltype(INTOT0)::value ? T0[i] : T1[i];
            float tp1 = decltype(INTOT0)::value ? T1[i] : T0[i];
            float c2 = (i == 0) ? 2.0f : ((i <= 6) ? Bs[i - 1] : -Bs[12 - i]);
            float t = fmaf(c2, tp1, -tp2);
            float kc = (i == 0) ? As[13] : As[i];
            t = (i & 1) ? fmaf(-kc, Po, t) : fmaf(kc, Pe, t);
            if constexpr (decltype(INTOT0)::value) T0[i] = t; else T1[i] = t;
        }
        if constexpr (decltype(INTOT0)::value) sf(T0, rt); else sf(T1, rt);
    };

    // ---- ramp1: fill Rv + diff ring, k=0..11 (6 pairs) ----
    { float Rn = front(xvA, xvB); Rprev = Rn; pushRv(Rn); }
    { float Rn = front(xvB, xvA); pushd(Rn); pushRv(Rn); }
#pragma unroll 1
    for (int k = 2; k < 12; k += 2) {
        float Rn = front(xvA, xvB); pushd(Rn); pushRv(Rn);
        float Rm = front(xvB, xvA); pushd(Rm); pushRv(Rm);
    }
    // ---- bootstrap: direct matvecs at k=12,13 ----
    { float Rn = front(xvA, xvB); pushd(Rn); pushRv(Rn); matvec(T0); sf(T0, false); }
    { float Rn = front(xvB, xvA); pushd(Rn); pushRv(Rn); matvec(T1); sf(T1, false); }
    // ---- steady: recurrence pairs; retire from steady-step 10 on ----
    {
        int ks = 0; const int S = 10 + segrows;
#pragma unroll 1
        while (ks + 2 <= S) {
            recur(TrueT{},  xvA, xvB, ks     >= 10);
            recur(FalseT{}, xvB, xvA, ks + 1 >= 10);
            ks += 2;
        }
        if (ks < S) recur(TrueT{}, xvA, xvB, ks >= 10);
    }
}

__global__ __launch_bounds__(256) void dct2net_k3(
    const float* __restrict__ Hg, const float* __restrict__ Wg,
    const float* __restrict__ sigmag, float* __restrict__ outg)
{
    __shared__ float U[4][76][15];   // stride 15: diag read 2-way alias (free)
    __shared__ float vw[4][80];
    const int tid  = threadIdx.x;
    const int lane = tid & 63;
    const int wv   = tid >> 6;
    const int img  = blockIdx.z;
    const int a0   = blockIdx.y * 4;
    const int a    = a0 + wv;               // out row (<= 487)
    const int cb   = blockIdx.x * 64;       // out col base

    const float t3s = 3.0f * sigmag[0];     // undo k2's scaled domain

    float As[14];
#pragma unroll
    for (int q = 0; q < 14; ++q) As[q] = ctab.a[q];
#pragma unroll
    for (int q = 0; q < 14; ++q) asm("" : "+s"(As[q]));

    // ---- coalesced loads from jj-plane Hg: 13 x 256B-contiguous ----
    int c = cb + lane; c = (c < 499) ? c : 499;
    const float* hb = Hg + ((size_t)img * OUTW + a) * HPITCH * HCOLS + c;
    float hv[P13];
#pragma unroll
    for (int j = 0; j < P13; ++j) hv[j] = hb[j * HCOLS];
    float wm = Wg[((size_t)img * IMGW + a) * IMGW + c];

    const bool halo = (tid < 48);           // wave 0: 4 rows x 12 halo cols
    const int  hr = tid / 12;
    const int  hm = tid - hr * 12;
    float sv[P13]; float ws = 0.0f;
#pragma unroll
    for (int j = 0; j < P13; ++j) sv[j] = 0.0f;
    if (halo) {
        const int ah = a0 + hr;
        int c2 = cb + 64 + hm; c2 = (c2 < 499) ? c2 : 499;
        const float* hq = Hg + ((size_t)img * OUTW + ah) * HPITCH * HCOLS + c2;
#pragma unroll
        for (int j = 0; j < P13; ++j) sv[j] = hq[j * HCOLS];
        ws = Wg[((size_t)img * IMGW + ah) * IMGW + c2];
    }

    // U build with row symmetry: c1[12-dy][j] = (-1)^j c1[dy][j]
    auto buildU = [&](const float (&h)[P13], int uw, int uli) {
#pragma unroll
        for (int dy = 0; dy < 6; ++dy) {
            float e = KC(dy, 0) * h[0];
#pragma unroll
            for (int j = 2; j < P13; j += 2) e = fmaf(KC(dy, j), h[j], e);
            float o = KC(dy, 1) * h[1];
#pragma unroll
            for (int j = 3; j < P13; j += 2) o = fmaf(KC(dy, j), h[j], o);
            U[uw][uli][dy]      = e + o;
            U[uw][uli][12 - dy] = e - o;
        }
        float gsum = ((h[4] - h[2]) + (h[8] - h[6])) + (h[12] - h[10]);
        U[uw][uli][6] = fmaf(As[0], gsum, As[13] * h[0]);
    };

    buildU(hv, wv, lane);
    vw[wv][lane] = wm;
    if (halo) {
        buildU(sv, hr, 64 + hm);
        vw[hr][64 + hm] = ws;
    }
    __syncthreads();

    float num = 0.0f;
#pragma unroll
    for (int dy = 0; dy < P13; ++dy) num += U[wv][lane + 12 - dy][dy];
    float den = 0.0f;
#pragma unroll
    for (int d = 0; d < P13; ++d) den += vw[wv][lane + d];
    const int ow = cb + lane;
    if (ow < OUTW)
        outg[((size_t)img * OUTW + a) * OUTW + ow] =
            num * t3s * __builtin_amdgcn_rcpf(den);
}

extern "C" void kernel_launch(void* const* d_in, const int* in_sizes, int n_in,
                              void* d_out, int out_size, void* d_ws, size_t ws_size,
                              hipStream_t stream)
{
    const float* x     = (const float*)d_in[0];
    const float* sigma = (const float*)d_in[1];
    float* out = (float*)d_out;

    // ws: Hg (2*488*16*512 f32 = 31.98 MB) then Wg (2*512*512 f32 = 2 MB)
    float* Hg = (float*)d_ws;
    float* Wg = Hg + (size_t)2 * OUTW * HPITCH * HCOLS;

    dct2net_k2<<<dim3(32, NSEG, 2), 256, 0, stream>>>(x, sigma, Hg, Wg);
    dct2net_k3<<<dim3(8, 122, 2), 256, 0, stream>>>(Hg, Wg, sigma, out);
}

// Round 7
// 176.396 us; speedup vs baseline: 1.0237x; 1.0015x over previous
//
#include <hip/hip_runtime.h>
#include <math.h>

// DCT2net, R12: software-pipelined window gather + conflict-free xlds +
// single-wave k3 (no barrier, 7808 blocks).
//
// R11 post-mortem: k2 129->120.5us (gather path = real bottleneck). Remaining:
// VALUBusy 78%, 454K bank conflicts (stride-20 xlds write = 3-way alias), and
// the step-serial ds_write->ds_read_b128->FMA chain. Also: total-k2 ~= 50us
// constant across 6 rounds regardless of k3 changes -> this round's k3
// restructure (single-wave, max TLP) is a diagnostic: if the gap persists,
// it's harness overhead and k3 is done.
//
// R12:
//  - persistent xq[16] window registers: step k consumes regs read at step
//    k-1; ds_write + 4x ds_read_b128 for row k+1 issue AFTER the hDCT -> one
//    full step (~1000cyc) of lgkm slack. No LDS wait at step top.
//  - xlds [4][4][16]: write = exactly 2 lanes/bank (free), b128 reads = 2-way
//    broadcast alias (free). 454K conflicts -> ~0.
//  - k3: 1 wave/block, 1 row x 64 cols, grid (8,488,2): no __syncthreads,
//    ~30 waves/CU latency hiding. LDS 4.9KB/block.
//  - keeps R10/R11: sliding-DCT recurrence, scaled domain, SGPR const pools,
//    DPP ROR16, runtime retire, jj-plane Hg, pair-unrolled T0/T1.
//
// ws: Hg = 2*488*16*512 f32 (31.98 MB), Wg = 2*512*512 f32 (2 MB).

#define P13    13
#define IMGW   512
#define OUTW   488
#define SEGH   31      // 15*31 + 23 = 488
#define NSEG   16
#define HCOLS  512
#define HPITCH 16

struct C1mat { float v[P13 * P13]; };

// ---- compile-time DCT tables ----
constexpr double kPI = 3.14159265358979323846264338327950288;

constexpr double ccos_pm_pi(double th) {   // Taylor, |th| <= pi
    double term = 1.0, s = 1.0;
    const double th2 = th * th;
    for (int n = 1; n <= 25; ++n) {
        term *= -th2 / (double)((2 * n - 1) * (2 * n));
        s += term;
    }
    return s;
}
constexpr double csqrt(double v) {
    double x = (v > 1.0) ? v : 1.0;
    for (int i = 0; i < 64; ++i) x = 0.5 * (x + v / x);
    return x;
}
constexpr C1mat make_c1() {
    C1mat m{};
    const double s213 = csqrt(2.0 / 13.0);
    const double is2  = 1.0 / csqrt(2.0);
    for (int x = 0; x < P13; ++x)
        for (int k = 0; k < P13; ++k) {
            int mm = ((2 * x + 1) * k) % 52;
            double th = (mm <= 26) ? (mm * kPI / 26.0) : ((mm - 52) * kPI / 26.0);
            double Ci = (k == 0) ? is2 : 1.0;
            m.v[x * P13 + k] = (float)(s213 * Ci * ccos_pm_pi(th));
        }
    return m;
}
__device__ constexpr C1mat c1c = make_c1();

// c1[r][c] = sgn*A[idx]; A[q] = s213*cos(q*pi/26) (q=0..12), A[13] = s213/sqrt2.
// b[q] = 2*cos((q+1)*pi/13), q=0..5 (sliding-DCT recurrence constants).
struct CTab { int idx[P13][P13]; bool neg[P13][P13]; float a[14]; float b[6]; };
constexpr CTab make_ctab() {
    CTab t{};
    const double s213 = csqrt(2.0 / 13.0);
    for (int q = 0; q <= 12; ++q) t.a[q] = (float)(s213 * ccos_pm_pi(q * kPI / 26.0));
    t.a[13] = (float)(s213 / csqrt(2.0));
    for (int q = 0; q < 6; ++q) t.b[q] = (float)(2.0 * ccos_pm_pi((q + 1) * kPI / 13.0));
    for (int r = 0; r < P13; ++r)
        for (int c = 0; c < P13; ++c) {
            if (c == 0) { t.idx[r][c] = 13; t.neg[r][c] = false; continue; }
            int m = ((2 * r + 1) * c) % 52;
            int q; bool n;
            if (m <= 13)      { q = m;      n = false; }
            else if (m <= 26) { q = 26 - m; n = true;  }
            else if (m <= 39) { q = m - 26; n = true;  }
            else              { q = 52 - m; n = false; }
            t.idx[r][c] = q; t.neg[r][c] = n;
        }
    return t;
}
constexpr CTab ctab = make_ctab();

#define KC(r, c) (ctab.neg[(r)][(c)] ? -As[ctab.idx[(r)][(c)]] : As[ctab.idx[(r)][(c)]])

struct FalseT { static constexpr bool value = false; };
struct TrueT  { static constexpr bool value = true; };

// rotate-reduce add within each 16-lane DPP row: N in {1,2,4,8}
#define ROR16_ADD(v, N)                                                        \
    v += __int_as_float(__builtin_amdgcn_mov_dpp(__float_as_int(v),            \
                                                 0x120 + (N), 0xF, 0xF, true))

// weighted vertical inverse fold (scaled domain)
__device__ __forceinline__ void fold_vert(const float (&tn)[P13], const float (&As)[14],
                                          float w1, float (&H)[P13])
{
#pragma unroll
    for (int dx = 0; dx < 6; ++dx) {
        float E = KC(dx, 0) * tn[0];
#pragma unroll
        for (int i = 2; i < P13; i += 2) E = fmaf(KC(dx, i), tn[i], E);
        float O = KC(dx, 1) * tn[1];
#pragma unroll
        for (int i = 3; i < P13; i += 2) O = fmaf(KC(dx, i), tn[i], O);
        H[dx]      = fmaf(w1, E + O, H[dx]);
        H[12 - dx] = fmaf(w1, E - O, H[12 - dx]);
    }
    float z6 = KC(6, 0) * tn[0];
#pragma unroll
    for (int i = 2; i < P13; i += 2) z6 = fmaf(KC(6, i), tn[i], z6);
    H[6] = fmaf(w1, z6, H[6]);
}

__global__ __launch_bounds__(256) void dct2net_k2(
    const float* __restrict__ xg, const float* __restrict__ sigmag,
    float* __restrict__ Hg, float* __restrict__ Wg)
{
    __shared__ float c1lds[169];
    __shared__ float xlds[4][4][16];       // stride 16: 2 lanes/bank = free
    const int tid = threadIdx.x;
    if (tid < 169) c1lds[tid] = c1c.v[tid];
    __syncthreads();                       // once, for the c1 table only

    const int lane = tid & 63;
    const int wv   = tid >> 6;
    const int g    = lane >> 4;            // col group 0..3
    const int jj   = lane & 15;            // kj (0..12 used)
    const int img  = blockIdx.z;
    const int hs   = blockIdx.y * SEGH;
    const int segrows = (OUTW - hs < SEGH) ? (OUTW - hs) : SEGH;
    const int cbw  = blockIdx.x * 16 + wv * 4;
    const int col  = cbw + g;

    const float inv3s = 1.0f / (3.0f * sigmag[0]);
    const float* xin  = xg + (size_t)img * IMGW * IMGW;

    // SGPR constant pools
    float As[14], Bs[6];
#pragma unroll
    for (int q = 0; q < 14; ++q) As[q] = ctab.a[q];
#pragma unroll
    for (int q = 0; q < 6; ++q) Bs[q] = ctab.b[q];
#pragma unroll
    for (int q = 0; q < 14; ++q) asm("" : "+s"(As[q]));
#pragma unroll
    for (int q = 0; q < 6; ++q) asm("" : "+s"(Bs[q]));

    // per-lane window coefficients over staged positions p=0..15:
    // c1x[p] = c1[p-g][jj] * inv3s inside the window, 0 outside / idle lanes
    float c1x[16];
#pragma unroll
    for (int p = 0; p < 16; ++p) {
        int y = p - g;
        int yc = (y < 0) ? 0 : ((y > 12) ? 12 : y);
        int jc = (jj < 13) ? jj : 0;
        float v = c1lds[yc * 13 + jc];
        c1x[p] = (y >= 0 && y < 13 && jj < 13) ? v * inv3s : 0.0f;
    }

    float T0[P13], T1[P13], dr[P13], Hr[P13], wr[12], Rv[P13];
#pragma unroll
    for (int k = 0; k < P13; ++k) { T0[k]=0; T1[k]=0; dr[k]=0; Hr[k]=0; Rv[k]=0; }
#pragma unroll
    for (int k = 0; k < 12; ++k) wr[k] = 0.0f;
    float vs = 0.0f, Rprev = 0.0f;

    int xcol = cbw + (lane & 15); xcol = (xcol < IMGW - 1) ? xcol : (IMGW - 1);
    const float* xlast = xin + (size_t)(IMGW - 1) * IMGW;

    // ---- pre-roll: stage row hs, read its window into xq, xvA <- row hs+1 ----
    float xq[16];
    float xvA, xvB;
    {
        const float* r0 = xin + (size_t)hs * IMGW;
        xlds[wv][g][jj] = r0[xcol];
        float4 q0 = *(const float4*)&xlds[wv][g][0];
        float4 q1 = *(const float4*)&xlds[wv][g][4];
        float4 q2 = *(const float4*)&xlds[wv][g][8];
        float4 q3 = *(const float4*)&xlds[wv][g][12];
        xq[0]=q0.x; xq[1]=q0.y; xq[2]=q0.z; xq[3]=q0.w;
        xq[4]=q1.x; xq[5]=q1.y; xq[6]=q1.z; xq[7]=q1.w;
        xq[8]=q2.x; xq[9]=q2.y; xq[10]=q2.z; xq[11]=q2.w;
        xq[12]=q3.x; xq[13]=q3.y; xq[14]=q3.z; xq[15]=q3.w;
        const float* r1 = xin + (size_t)(hs + 1) * IMGW;
        xvA = r1[xcol];
    }
    const float* xp = xin + (size_t)(hs + 2) * IMGW;

    float* Hp = Hg + ((size_t)img * OUTW + hs) * HPITCH * HCOLS;
    float* Wp = Wg + ((size_t)img * IMGW + hs) * IMGW;
    const int voH = jj * HCOLS + col;      // jj-plane layout
    const int voW = col;

    // hDCT of the CURRENT row from the pipelined window registers
    auto hdct = [&]() -> float {
        float a0 = c1x[0] * xq[0], a1 = c1x[1] * xq[1];
#pragma unroll
        for (int p = 2; p < 16; p += 2) a0 = fmaf(c1x[p], xq[p], a0);
#pragma unroll
        for (int p = 3; p < 16; p += 2) a1 = fmaf(c1x[p], xq[p], a1);
        return a0 + a1;
    };
    // stage NEXT row (xvW) to LDS, read its window into xq (latency hidden
    // under the rest of this step + next step's front), prefetch row after.
    auto advance = [&](float xvW, float& xvL) {
        xlds[wv][g][jj] = xvW;
        float4 q0 = *(const float4*)&xlds[wv][g][0];
        float4 q1 = *(const float4*)&xlds[wv][g][4];
        float4 q2 = *(const float4*)&xlds[wv][g][8];
        float4 q3 = *(const float4*)&xlds[wv][g][12];
        xq[0]=q0.x; xq[1]=q0.y; xq[2]=q0.z; xq[3]=q0.w;
        xq[4]=q1.x; xq[5]=q1.y; xq[6]=q1.z; xq[7]=q1.w;
        xq[8]=q2.x; xq[9]=q2.y; xq[10]=q2.z; xq[11]=q2.w;
        xq[12]=q3.x; xq[13]=q3.y; xq[14]=q3.z; xq[15]=q3.w;
        const float* xr = (xp < xlast) ? xp : xlast;
        xvL = xr[xcol]; xp += IMGW;
    };
    auto pushRv = [&](float Rn) {
#pragma unroll
        for (int q = 0; q < P13 - 1; ++q) Rv[q] = Rv[q + 1];
        Rv[P13 - 1] = Rn;
    };
    auto pushd = [&](float Rn) {
        float dn = Rn - Rprev; Rprev = Rn;
#pragma unroll
        for (int q = 0; q < P13 - 1; ++q) dr[q] = dr[q + 1];
        dr[P13 - 1] = dn;
    };
    auto matvec = [&](float (&T)[P13]) {   // bootstrap only
        float Se[6], So[6];
#pragma unroll
        for (int k = 0; k < 6; ++k) { Se[k] = Rv[k] + Rv[12 - k]; So[k] = Rv[k] - Rv[12 - k]; }
#pragma unroll
        for (int i = 0; i < P13; ++i) {
            float t;
            if ((i & 1) == 0) {
                t = KC(6, i) * Rv[6];
#pragma unroll
                for (int k = 0; k < 6; ++k) t = fmaf(KC(k, i), Se[k], t);
            } else {
                t = KC(0, i) * So[0];
#pragma unroll
                for (int k = 1; k < 6; ++k) t = fmaf(KC(k, i), So[k], t);
            }
            T[i] = t;
        }
    };
    // shrink + butterfly + fold + (runtime) retire. T pre-scaled (u = t).
    auto sf = [&](const float (&T)[P13], bool rt) {
        float tn[P13]; float pnzr = 0.0f;
#pragma unroll
        for (int i = 0; i < P13; ++i) {
            float p2 = fminf(T[i] * T[i], 1.69f);
            float p4 = p2 * p2, p8 = p4 * p4, p16 = p8 * p8, p32 = p16 * p16, p64 = p32 * p32;
            float r  = __builtin_amdgcn_rcpf(p64 + 1.0f);
            pnzr += r;
            tn[i] = fmaf(-T[i], r, T[i]);
        }
        float pnz = 13.0f - pnzr;          // idle lanes: exactly 0
        ROR16_ADD(pnz, 1); ROR16_ADD(pnz, 2); ROR16_ADD(pnz, 4); ROR16_ADD(pnz, 8);
        const float w = __builtin_amdgcn_rcpf(1.0f + pnz);
        vs += w;
        fold_vert(tn, As, w, Hr);
        if (rt) {                           // uniform branch
            Hp[voH] = Hr[0];
            Hp += HPITCH * HCOLS;
            if (jj == 0) Wp[voW] = vs;
            Wp += IMGW;
            vs -= wr[0];
        }
#pragma unroll
        for (int q = 0; q < 11; ++q) wr[q] = wr[q + 1];
        wr[11] = w;
#pragma unroll
        for (int q = 0; q < P13 - 1; ++q) Hr[q] = Hr[q + 1];
        Hr[P13 - 1] = 0.0f;
    };
    auto recur = [&](auto INTOT0, float& xvW, float& xvL, bool rt) {
        float Rn = hdct();
        advance(xvW, xvL);
        float dn = Rn - Rprev; Rprev = Rn;
        float dl = dr[0];
#pragma unroll
        for (int q = 0; q < P13 - 1; ++q) dr[q] = dr[q + 1];
        dr[P13 - 1] = dn;
        float Pe = dn - dl, Po = dn + dl;
#pragma unroll
        for (int i = 0; i < P13; ++i) {
            float tp2 = decltype(INTOT0)::value ? T0[i] : T1[i];
            float tp1 = decltype(INTOT0)::value ? T1[i] : T0[i];
            float c2 = (i == 0) ? 2.0f : ((i <= 6) ? Bs[i - 1] : -Bs[12 - i]);
            float t = fmaf(c2, tp1, -tp2);
            float kc = (i == 0) ? As[13] : As[i];
            t = (i & 1) ? fmaf(-kc, Po, t) : fmaf(kc, Pe, t);
            if constexpr (decltype(INTOT0)::value) T0[i] = t; else T1[i] = t;
        }
        if constexpr (decltype(INTOT0)::value) sf(T0, rt); else sf(T1, rt);
    };

    // ---- ramp1: k=0..11 (even k -> xvA staged, odd k -> xvB) ----
    { float Rn = hdct(); advance(xvA, xvB); Rprev = Rn; pushRv(Rn); }
    { float Rn = hdct(); advance(xvB, xvA); pushd(Rn); pushRv(Rn); }
#pragma unroll 1
    for (int k = 2; k < 12; k += 2) {
        float Rn = hdct(); advance(xvA, xvB); pushd(Rn); pushRv(Rn);
        float Rm = hdct(); advance(xvB, xvA); pushd(Rm); pushRv(Rm);
    }
    // ---- bootstrap: direct matvecs at k=12,13 ----
    { float Rn = hdct(); advance(xvA, xvB); pushd(Rn); pushRv(Rn); matvec(T0); sf(T0, false); }
    { float Rn = hdct(); advance(xvB, xvA); pushd(Rn); pushRv(Rn); matvec(T1); sf(T1, false); }
    // ---- steady: recurrence pairs; retire from steady-step 10 on ----
    {
        int ks = 0; const int S = 10 + segrows;
#pragma unroll 1
        while (ks + 2 <= S) {
            recur(TrueT{},  xvA, xvB, ks     >= 10);
            recur(FalseT{}, xvB, xvA, ks + 1 >= 10);
            ks += 2;
        }
        if (ks < S) recur(TrueT{}, xvA, xvB, ks >= 10);
    }
}

__global__ __launch_bounds__(64) void dct2net_k3(
    const float* __restrict__ Hg, const float* __restrict__ Wg,
    const float* __restrict__ sigmag, float* __restrict__ outg)
{
    __shared__ float U[76][15];      // stride 15: diag read 2-way alias (free)
    __shared__ float vw[80];
    const int lane = threadIdx.x;    // single wave per block
    const int img  = blockIdx.z;
    const int a    = blockIdx.y;     // out row 0..487
    const int cb   = blockIdx.x * 64;

    const float t3s = 3.0f * sigmag[0];     // undo k2's scaled domain

    float As[14];
#pragma unroll
    for (int q = 0; q < 14; ++q) As[q] = ctab.a[q];
#pragma unroll
    for (int q = 0; q < 14; ++q) asm("" : "+s"(As[q]));

    // ---- coalesced loads from jj-plane Hg (main + halo issued up front) ----
    int c = cb + lane; c = (c < 499) ? c : 499;
    const float* hb = Hg + ((size_t)img * OUTW + a) * HPITCH * HCOLS + c;
    float hv[P13];
#pragma unroll
    for (int j = 0; j < P13; ++j) hv[j] = hb[j * HCOLS];
    float wm = Wg[((size_t)img * IMGW + a) * IMGW + c];

    const bool halo = (lane < 12);
    float sv[P13]; float ws = 0.0f;
#pragma unroll
    for (int j = 0; j < P13; ++j) sv[j] = 0.0f;
    if (halo) {
        int c2 = cb + 64 + lane; c2 = (c2 < 499) ? c2 : 499;
        const float* hq = Hg + ((size_t)img * OUTW + a) * HPITCH * HCOLS + c2;
#pragma unroll
        for (int j = 0; j < P13; ++j) sv[j] = hq[j * HCOLS];
        ws = Wg[((size_t)img * IMGW + a) * IMGW + c2];
    }

    // U build with row symmetry: c1[12-dy][j] = (-1)^j c1[dy][j]
    auto buildU = [&](const float (&h)[P13], int uli) {
#pragma unroll
        for (int dy = 0; dy < 6; ++dy) {
            float e = KC(dy, 0) * h[0];
#pragma unroll
            for (int j = 2; j < P13; j += 2) e = fmaf(KC(dy, j), h[j], e);
            float o = KC(dy, 1) * h[1];
#pragma unroll
            for (int j = 3; j < P13; j += 2) o = fmaf(KC(dy, j), h[j], o);
            U[uli][dy]      = e + o;
            U[uli][12 - dy] = e - o;
        }
        float gsum = ((h[4] - h[2]) + (h[8] - h[6])) + (h[12] - h[10]);
        U[uli][6] = fmaf(As[0], gsum, As[13] * h[0]);
    };

    buildU(hv, lane);
    vw[lane] = wm;
    if (halo) {
        buildU(sv, 64 + lane);
        vw[64 + lane] = ws;
    }
    // single wave: LDS write->read in program order, no barrier

    float num = 0.0f;
#pragma unroll
    for (int dy = 0; dy < P13; ++dy) num += U[lane + 12 - dy][dy];
    float den = 0.0f;
#pragma unroll
    for (int d = 0; d < P13; ++d) den += vw[lane + d];
    const int ow = cb + lane;
    if (ow < OUTW)
        outg[((size_t)img * OUTW + a) * OUTW + ow] =
            num * t3s * __builtin_amdgcn_rcpf(den);
}

extern "C" void kernel_launch(void* const* d_in, const int* in_sizes, int n_in,
                              void* d_out, int out_size, void* d_ws, size_t ws_size,
                              hipStream_t stream)
{
    const float* x     = (const float*)d_in[0];
    const float* sigma = (const float*)d_in[1];
    float* out = (float*)d_out;

    // ws: Hg (2*488*16*512 f32 = 31.98 MB) then Wg (2*512*512 f32 = 2 MB)
    float* Hg = (float*)d_ws;
    float* Wg = Hg + (size_t)2 * OUTW * HPITCH * HCOLS;

    dct2net_k2<<<dim3(32, NSEG, 2), 256, 0, stream>>>(x, sigma, Hg, Wg);
    dct2net_k3<<<dim3(8, 488, 2), 64, 0, stream>>>(Hg, Wg, sigma, out);
}